// Round 6
// baseline (281.107 us; speedup 1.0000x reference)
//
#include <hip/hip_runtime.h>
#include <hip/hip_bf16.h>

#define NROWS 32768
#define DDIM  4096
#define ODIM  256
#define EPSV  1e-5f

#define CHUNKS 128
#define RPC    256      // rows per chunk (CHUNKS*RPC == NROWS)

#define BM 128
#define BK 64
#define NKT (DDIM / BK)   // 64 K-steps

typedef __attribute__((ext_vector_type(4))) float          f32x4;
typedef __attribute__((ext_vector_type(8))) __bf16         bf16x8;
typedef __attribute__((ext_vector_type(8))) unsigned short u16x8;
typedef __attribute__((ext_vector_type(4))) unsigned short u16x4;

static __device__ __forceinline__ unsigned short f2bf(float f) {
  return __builtin_bit_cast(unsigned short, __float2bfloat16(f));
}
static __device__ __forceinline__ float bf2f(unsigned short u) {
  return __builtin_bit_cast(float, ((unsigned)u) << 16);
}

// ---------------- k1: column partial sums + bf16 copy of x ----------------
__global__ __launch_bounds__(256) void k1_stats(const float* __restrict__ x,
                                                float* __restrict__ psum,
                                                float* __restrict__ psq,
                                                unsigned short* __restrict__ xb) {
  const int col = blockIdx.x * 1024 + threadIdx.x * 4;
  const size_t base = (size_t)blockIdx.y * RPC * DDIM + col;
  const float* p = x + base;
  unsigned short* xo = xb + base;
  f32x4 s = {0.f, 0.f, 0.f, 0.f};
  f32x4 q = {0.f, 0.f, 0.f, 0.f};
#pragma unroll 8
  for (int r = 0; r < RPC; ++r) {
    f32x4 v = *(const f32x4*)p;
    p += DDIM;
    s += v;
    q += v * v;
    u16x4 o;
    o[0] = f2bf(v[0]); o[1] = f2bf(v[1]); o[2] = f2bf(v[2]); o[3] = f2bf(v[3]);
    *(u16x4*)xo = o;
    xo += DDIM;
  }
  *(f32x4*)(psum + (size_t)blockIdx.y * DDIM + col) = s;
  *(f32x4*)(psq  + (size_t)blockIdx.y * DDIM + col) = q;
}

// ---------------- k2a: finalize mean/var -> scale/shift ----------------
__global__ __launch_bounds__(256) void k2_stats_finalize(
    const float* __restrict__ psum, const float* __restrict__ psq,
    const float* __restrict__ gamma, const float* __restrict__ beta,
    float* __restrict__ scale, float* __restrict__ shift) {
  __shared__ float ss[4][64];
  __shared__ float sq[4][64];
  const int lane = threadIdx.x & 63;
  const int g    = threadIdx.x >> 6;          // 0..3
  const int d    = blockIdx.x * 64 + lane;
  float s = 0.f, qq = 0.f;
  for (int c = g * 32; c < (g + 1) * 32; ++c) {
    s  += psum[(size_t)c * DDIM + d];
    qq += psq [(size_t)c * DDIM + d];
  }
  ss[g][lane] = s;
  sq[g][lane] = qq;
  __syncthreads();
  if (g == 0) {
    s  = ss[0][lane] + ss[1][lane] + ss[2][lane] + ss[3][lane];
    qq = sq[0][lane] + sq[1][lane] + sq[2][lane] + sq[3][lane];
    const float inv = 1.0f / (float)NROWS;
    const float mean = s * inv;
    const float var  = fmaxf(qq * inv - mean * mean, 0.f);
    const float a = gamma[d] * rsqrtf(var + EPSV);
    scale[d] = a;
    shift[d] = beta[d] - mean * a;
  }
}

// ---------------- k2b: W fp32 -> bf16 ----------------
__global__ __launch_bounds__(256) void k2_wconv(const float* __restrict__ Wf,
                                                unsigned short* __restrict__ Wb) {
  const size_t i = ((size_t)blockIdx.x * 256 + threadIdx.x) * 4;
  f32x4 v = *(const f32x4*)(Wf + i);
  u16x4 o;
  o[0] = f2bf(v[0]); o[1] = f2bf(v[1]); o[2] = f2bf(v[2]); o[3] = f2bf(v[3]);
  *(u16x4*)(Wb + i) = o;
}

// ---------------- k3: normalize+relu+GEMM from bf16 xb (R4 schedule) ----------
// Per step t: asm-issue A(t+1) (2x dwordx4 bf16) -> gl_lds B(t+1) -> MFMA(t)
//  -> vmcnt(4) [A done, B in flight] -> transform+ds_write A(t+1)
//  -> vmcnt(0)+lgkmcnt(0) -> s_barrier.
__global__ __launch_bounds__(512, 1) void k3_bn_gemm(
    const unsigned short* __restrict__ xb,
    const unsigned short* __restrict__ Wb,
    const float* __restrict__ scale,
    const float* __restrict__ shift,
    const float* __restrict__ bias,
    float* __restrict__ out) {
  __shared__ unsigned short As[2][BM * BK];     // 2 x 16 KB, XOR-swizzled
  __shared__ unsigned short Bs[2][ODIM * BK];   // 2 x 32 KB, XOR-swizzled
  __shared__ unsigned short SFb[DDIM];          // 8 KB scale (bf16)
  __shared__ unsigned short SHb[DDIM];          // 8 KB shift (bf16)

  const int tid = threadIdx.x;
  const int l   = tid & 63;
  const int w   = tid >> 6;     // 0..7
  const int wr  = w >> 2;       // 0..1
  const int wc  = w & 3;        // 0..3
  const size_t bm0 = (size_t)blockIdx.x * BM;

  // --- scale/shift preload -> bf16 LDS (each thread 8 cols) ---
  {
    const int c0 = tid * 8;
    f32x4 s0 = *(const f32x4*)(scale + c0);
    f32x4 s1 = *(const f32x4*)(scale + c0 + 4);
    f32x4 h0 = *(const f32x4*)(shift + c0);
    f32x4 h1 = *(const f32x4*)(shift + c0 + 4);
    u16x8 os, oh;
#pragma unroll
    for (int e = 0; e < 4; ++e) {
      os[e] = f2bf(s0[e]); os[e + 4] = f2bf(s1[e]);
      oh[e] = f2bf(h0[e]); oh[e + 4] = f2bf(h1[e]);
    }
    *(u16x8*)&SFb[c0] = os;
    *(u16x8*)&SHb[c0] = oh;
  }

  // --- A staging geometry: thread covers row rA (0..127), 16-col unit uA ---
  const int rA = tid >> 2;      // 0..127
  const int uA = tid & 3;       // 0..3  (16 bf16 = 32 B per unit)
  const unsigned short* xp = xb + (bm0 + rA) * (size_t)DDIM + uA * 16;
  const int sw = rA & 7;
  const int aw0 = rA * 64 + (((uA * 2)     ^ sw) << 3);   // ushort offsets
  const int aw1 = rA * 64 + (((uA * 2 + 1) ^ sw) << 3);
  int ktb = uA * 16;            // scale/shift col base, += 64 per step

  // --- B staging: gl_lds, linear LDS dest + inverse-swizzled global src ---
  const unsigned short* bsrc[4];
#pragma unroll
  for (int q = 0; q < 4; ++q) {
    const int p  = w * 256 + q * 64 + l;
    const int o  = p >> 3;
    const int up = p & 7;
    bsrc[q] = Wb + (size_t)o * DDIM + ((up ^ (o & 7)) << 3);
  }

  // --- fragment LDS offsets (ushort units); kk -> ^32 ---
  int offA[4], offB[4];
#pragma unroll
  for (int i = 0; i < 4; ++i) {
    const int row = wr * 64 + i * 16 + (l & 15);
    offA[i] = row * 64 + (((l >> 4) ^ (row & 7)) << 3);
  }
#pragma unroll
  for (int j = 0; j < 4; ++j) {
    const int row = wc * 64 + j * 16 + (l & 15);
    offB[j] = row * 64 + (((l >> 4) ^ (row & 7)) << 3);
  }

  const f32x4 zero = {0.f, 0.f, 0.f, 0.f};
  f32x4 acc[4][4];
#pragma unroll
  for (int i = 0; i < 4; ++i)
#pragma unroll
    for (int j = 0; j < 4; ++j) acc[i][j] = zero;

#define ISSUE_A(S0, S1)                                                        \
  asm volatile("global_load_dwordx4 %0, %1, off" : "=v"(S0) : "v"(xp));        \
  asm volatile("global_load_dwordx4 %0, %1, off" : "=v"(S1) : "v"(xp + 8));    \
  xp += BK;                                                                    \
  asm volatile("" ::: "memory");

#define ISSUE_B(BUFI)                                                          \
  _Pragma("unroll")                                                            \
  for (int q = 0; q < 4; ++q) {                                                \
    __builtin_amdgcn_global_load_lds(                                          \
        (__attribute__((address_space(1))) void*)bsrc[q],                      \
        (__attribute__((address_space(3))) void*)(                             \
            &Bs[BUFI][(w * 256 + q * 64) * 8]),                                \
        16, 0, 0);                                                             \
    bsrc[q] += BK;                                                             \
  }                                                                            \
  asm volatile("" ::: "memory");

#define TRANSFORM_WRITE(BUFI, S0, S1)                                          \
  {                                                                            \
    u16x8 a0 = *(const u16x8*)&SFb[ktb];                                       \
    u16x8 a1 = *(const u16x8*)&SFb[ktb + 8];                                   \
    u16x8 c0 = *(const u16x8*)&SHb[ktb];                                       \
    u16x8 c1 = *(const u16x8*)&SHb[ktb + 8];                                   \
    ktb += BK;                                                                 \
    u16x8 pk0, pk1;                                                            \
    _Pragma("unroll")                                                          \
    for (int e = 0; e < 8; ++e) {                                              \
      pk0[e] = f2bf(fmaxf(bf2f(S0[e]) * bf2f(a0[e]) + bf2f(c0[e]), 0.f));      \
      pk1[e] = f2bf(fmaxf(bf2f(S1[e]) * bf2f(a1[e]) + bf2f(c1[e]), 0.f));      \
    }                                                                          \
    *(u16x8*)&As[BUFI][aw0] = pk0;                                             \
    *(u16x8*)&As[BUFI][aw1] = pk1;                                             \
  }

#define MFMA_PHASE(BUFI)                                                       \
  _Pragma("unroll")                                                            \
  for (int kk = 0; kk < 2; ++kk) {                                             \
    const int kx = kk << 5;                                                    \
    bf16x8 af[4], bfr[4];                                                      \
    _Pragma("unroll")                                                          \
    for (int i = 0; i < 4; ++i)                                                \
      af[i] = __builtin_bit_cast(bf16x8,                                       \
                                 *(const u16x8*)&As[BUFI][offA[i] ^ kx]);      \
    _Pragma("unroll")                                                          \
    for (int j = 0; j < 4; ++j)                                                \
      bfr[j] = __builtin_bit_cast(bf16x8,                                      \
                                  *(const u16x8*)&Bs[BUFI][offB[j] ^ kx]);     \
    _Pragma("unroll")                                                          \
    for (int i = 0; i < 4; ++i)                                                \
      _Pragma("unroll")                                                        \
      for (int j = 0; j < 4; ++j)                                              \
        acc[i][j] = __builtin_amdgcn_mfma_f32_16x16x32_bf16(                   \
            af[i], bfr[j], acc[i][j], 0, 0, 0);                                \
  }

  // ---- prologue: stage tile 0 into buffers [0] ----
  {
    u16x8 s0, s1;
    ISSUE_A(s0, s1);
    ISSUE_B(0);
    // SFb/SHb stores flushed, then block-wide visible
    asm volatile("s_waitcnt lgkmcnt(0)" ::: "memory");
    __builtin_amdgcn_sched_barrier(0);
    __builtin_amdgcn_s_barrier();
    asm volatile("s_waitcnt vmcnt(4)" ::: "memory");   // A0 landed, B0 flying
    __builtin_amdgcn_sched_barrier(0);
    TRANSFORM_WRITE(0, s0, s1);
    asm volatile("s_waitcnt vmcnt(0) lgkmcnt(0)" ::: "memory");
    __builtin_amdgcn_sched_barrier(0);
    __builtin_amdgcn_s_barrier();
  }

#define STEP(CUR, PF)                                                          \
  do {                                                                         \
    u16x8 s0, s1;                                                              \
    if (PF) {                                                                  \
      ISSUE_A(s0, s1);                                                         \
      ISSUE_B((CUR) ^ 1);                                                      \
    }                                                                          \
    MFMA_PHASE(CUR);                                                           \
    if (PF) {                                                                  \
      asm volatile("s_waitcnt vmcnt(4)" ::: "memory");                         \
      __builtin_amdgcn_sched_barrier(0);                                       \
      TRANSFORM_WRITE((CUR) ^ 1, s0, s1);                                      \
    }                                                                          \
    asm volatile("s_waitcnt vmcnt(0) lgkmcnt(0)" ::: "memory");                \
    __builtin_amdgcn_sched_barrier(0);                                         \
    __builtin_amdgcn_s_barrier();                                              \
  } while (0)

  for (int kt = 0; kt < NKT - 2; kt += 2) {
    STEP(0, true);
    STEP(1, true);
  }
  STEP(0, true);    // step 62, prefetch tile 63 into buf 1
  STEP(1, false);   // step 63
#undef STEP
#undef MFMA_PHASE
#undef TRANSFORM_WRITE
#undef ISSUE_B
#undef ISSUE_A

  // epilogue: C/D layout col=l&15, row=(l>>4)*4+rr
  const int cl = l & 15;
  const int rg = l >> 4;
#pragma unroll
  for (int j = 0; j < 4; ++j) {
    const int oc = wc * 64 + j * 16 + cl;
    const float bv = bias[oc];
#pragma unroll
    for (int i = 0; i < 4; ++i) {
      const size_t r0 = bm0 + wr * 64 + i * 16 + rg * 4;
#pragma unroll
      for (int rr = 0; rr < 4; ++rr) {
        out[(r0 + rr) * ODIM + oc] = acc[i][j][rr] + bv;
      }
    }
  }
}

extern "C" void kernel_launch(void* const* d_in, const int* in_sizes, int n_in,
                              void* d_out, int out_size, void* d_ws, size_t ws_size,
                              hipStream_t stream) {
  const float* x     = (const float*)d_in[0];
  const float* gamma = (const float*)d_in[1];
  const float* beta  = (const float*)d_in[2];
  const float* W     = (const float*)d_in[3];
  const float* b     = (const float*)d_in[4];
  float* out = (float*)d_out;

  // ws layout: xb bf16 [N*D] (256 MB) | psum | psq | scale | shift | Wb
  unsigned short* xbw = (unsigned short*)d_ws;
  float* psum  = (float*)(xbw + (size_t)NROWS * DDIM);
  float* psq   = psum + (size_t)CHUNKS * DDIM;
  float* scale = psq  + (size_t)CHUNKS * DDIM;
  float* shift = scale + DDIM;
  unsigned short* Wb = (unsigned short*)(shift + DDIM);

  k1_stats<<<dim3(4, CHUNKS), 256, 0, stream>>>(x, psum, psq, xbw);
  k2_stats_finalize<<<DDIM / 64, 256, 0, stream>>>(psum, psq, gamma, beta, scale, shift);
  k2_wconv<<<(ODIM * DDIM) / 1024, 256, 0, stream>>>(W, Wb);
  k3_bn_gemm<<<NROWS / BM, 512, 0, stream>>>(xbw, Wb, scale, shift, b, out);
}

// Round 7
// 256.715 us; speedup vs baseline: 1.0950x; 1.0950x over previous
//
#include <hip/hip_runtime.h>
#include <hip/hip_bf16.h>

#define NROWS 32768
#define DDIM  4096
#define ODIM  256
#define EPSV  1e-5f

#define CHUNKS 128
#define RPC    256      // rows per chunk (CHUNKS*RPC == NROWS)

#define BM 128
#define BK 64
#define NKT (DDIM / BK)   // 64 K-steps

typedef __attribute__((ext_vector_type(4))) float          f32x4;
typedef __attribute__((ext_vector_type(8))) __bf16         bf16x8;
typedef __attribute__((ext_vector_type(8))) unsigned short u16x8;
typedef __attribute__((ext_vector_type(4))) unsigned short u16x4;

static __device__ __forceinline__ unsigned short f2bf(float f) {
  return __builtin_bit_cast(unsigned short, __float2bfloat16(f));
}

// ---------------- k1: per-chunk column partial sums (R1-proven, ~86us) --------
__global__ __launch_bounds__(256) void k1_stats(const float* __restrict__ x,
                                                float* __restrict__ psum,
                                                float* __restrict__ psq) {
  const int col = blockIdx.x * 1024 + threadIdx.x * 4;
  const float* p = x + (size_t)blockIdx.y * RPC * DDIM + col;
  f32x4 s = {0.f, 0.f, 0.f, 0.f};
  f32x4 q = {0.f, 0.f, 0.f, 0.f};
#pragma unroll 8
  for (int r = 0; r < RPC; ++r) {
    f32x4 v = *(const f32x4*)p;
    p += DDIM;
    s += v;
    q += v * v;
  }
  *(f32x4*)(psum + (size_t)blockIdx.y * DDIM + col) = s;
  *(f32x4*)(psq  + (size_t)blockIdx.y * DDIM + col) = q;
}

// ---------------- k2a: finalize mean/var -> scale/shift ----------------
__global__ __launch_bounds__(256) void k2_stats_finalize(
    const float* __restrict__ psum, const float* __restrict__ psq,
    const float* __restrict__ gamma, const float* __restrict__ beta,
    float* __restrict__ scale, float* __restrict__ shift) {
  __shared__ float ss[4][64];
  __shared__ float sq[4][64];
  const int lane = threadIdx.x & 63;
  const int g    = threadIdx.x >> 6;          // 0..3
  const int d    = blockIdx.x * 64 + lane;
  float s = 0.f, qq = 0.f;
  for (int c = g * 32; c < (g + 1) * 32; ++c) {
    s  += psum[(size_t)c * DDIM + d];
    qq += psq [(size_t)c * DDIM + d];
  }
  ss[g][lane] = s;
  sq[g][lane] = qq;
  __syncthreads();
  if (g == 0) {
    s  = ss[0][lane] + ss[1][lane] + ss[2][lane] + ss[3][lane];
    qq = sq[0][lane] + sq[1][lane] + sq[2][lane] + sq[3][lane];
    const float inv = 1.0f / (float)NROWS;
    const float mean = s * inv;
    const float var  = fmaxf(qq * inv - mean * mean, 0.f);
    const float a = gamma[d] * rsqrtf(var + EPSV);
    scale[d] = a;
    shift[d] = beta[d] - mean * a;
  }
}

// ---------------- k2b: W fp32 -> bf16 ----------------
__global__ __launch_bounds__(256) void k2_wconv(const float* __restrict__ Wf,
                                                unsigned short* __restrict__ Wb) {
  const size_t i = ((size_t)blockIdx.x * 256 + threadIdx.x) * 4;
  f32x4 v = *(const f32x4*)(Wf + i);
  u16x4 o;
  o[0] = f2bf(v[0]); o[1] = f2bf(v[1]); o[2] = f2bf(v[2]); o[3] = f2bf(v[3]);
  *(u16x4*)(Wb + i) = o;
}

// ---------------- k3: wave-specialized normalize+relu+bf16 GEMM ----------------
// 768 threads: waves 0-7 CONSUME (ds_read + MFMA only), waves 8-11 PRODUCE
// (A global loads + affine/relu + ds_write, B global_load_lds, all vmcnt
// waits). One s_barrier per K-step; double-buffered As/Bs.
__global__ __launch_bounds__(768, 3) void k3_bn_gemm(
    const float* __restrict__ x,
    const unsigned short* __restrict__ Wb,
    const float* __restrict__ scale,
    const float* __restrict__ shift,
    const float* __restrict__ bias,
    float* __restrict__ out) {
  __shared__ unsigned short As[2][BM * BK];     // 2 x 16 KB, XOR-swizzled
  __shared__ unsigned short Bs[2][ODIM * BK];   // 2 x 32 KB, XOR-swizzled
  __shared__ float SF[DDIM];                    // 16 KB scale
  __shared__ float SH[DDIM];                    // 16 KB shift

  const int tid = threadIdx.x;
  const int l   = tid & 63;
  const size_t bm0 = (size_t)blockIdx.x * BM;
  const bool consumer = (tid < 512);

  // ================= consumer state =================
  const int w  = tid >> 6;      // 0..7 for consumers
  const int wr = w >> 2;        // 0..1
  const int wc = w & 3;         // 0..3
  int offA[4], offB[4];
#pragma unroll
  for (int i = 0; i < 4; ++i) {
    const int row = wr * 64 + i * 16 + (l & 15);
    offA[i] = row * 64 + (((l >> 4) ^ (row & 7)) << 3);
  }
#pragma unroll
  for (int j = 0; j < 4; ++j) {
    const int row = wc * 64 + j * 16 + (l & 15);
    offB[j] = row * 64 + (((l >> 4) ^ (row & 7)) << 3);
  }
  const f32x4 zero = {0.f, 0.f, 0.f, 0.f};
  f32x4 acc[4][4];
#pragma unroll
  for (int i = 0; i < 4; ++i)
#pragma unroll
    for (int j = 0; j < 4; ++j) acc[i][j] = zero;

  // ================= producer state =================
  const int p  = tid - 512;     // 0..255 for producers
  const int r0 = (p >> 3) & 31; // 0..31 (rows r0, r0+32, r0+64, r0+96)
  const int uA = p & 7;         // 8-col unit
  const float* xr0 = x + (bm0 + r0) * (size_t)DDIM + uA * 8;
  const float* xr1 = xr0 + (size_t)32 * DDIM;
  const float* xr2 = xr0 + (size_t)64 * DDIM;
  const float* xr3 = xr0 + (size_t)96 * DDIM;
  const int awo = r0 * 64 + ((uA ^ (r0 & 7)) << 3);   // ushort offset
  int ktb = uA * 8;                                   // scale/shift col base
  const unsigned short* bsrc[8];
#pragma unroll
  for (int q = 0; q < 8; ++q) {
    const int u  = q * 256 + p;      // 16B-unit index into a B buffer
    const int o  = u >> 3;           // W row 0..255
    const int up = u & 7;
    bsrc[q] = Wb + (size_t)o * DDIM + ((up ^ (o & 7)) << 3);
  }
  const int pwbase = (p & ~63);      // wave-uniform dest group

  // producer: preload scale/shift to LDS (16 cols per thread)
  if (!consumer) {
    const int c0 = p * 16;
#pragma unroll
    for (int e = 0; e < 4; ++e) {
      *(f32x4*)&SF[c0 + e * 4] = *(const f32x4*)(scale + c0 + e * 4);
      *(f32x4*)&SH[c0 + e * 4] = *(const f32x4*)(shift + c0 + e * 4);
    }
  }
  __syncthreads();   // SF/SH visible to producer waves

#define ISSUE_A8(S)                                                            \
  asm volatile("global_load_dwordx4 %0, %1, off"           : "=v"(S[0]) : "v"(xr0)); \
  asm volatile("global_load_dwordx4 %0, %1, off offset:16" : "=v"(S[1]) : "v"(xr0)); \
  asm volatile("global_load_dwordx4 %0, %1, off"           : "=v"(S[2]) : "v"(xr1)); \
  asm volatile("global_load_dwordx4 %0, %1, off offset:16" : "=v"(S[3]) : "v"(xr1)); \
  asm volatile("global_load_dwordx4 %0, %1, off"           : "=v"(S[4]) : "v"(xr2)); \
  asm volatile("global_load_dwordx4 %0, %1, off offset:16" : "=v"(S[5]) : "v"(xr2)); \
  asm volatile("global_load_dwordx4 %0, %1, off"           : "=v"(S[6]) : "v"(xr3)); \
  asm volatile("global_load_dwordx4 %0, %1, off offset:16" : "=v"(S[7]) : "v"(xr3)); \
  xr0 += BK; xr1 += BK; xr2 += BK; xr3 += BK;                                  \
  asm volatile("" ::: "memory");

#define ISSUE_B8(BUFI)                                                         \
  _Pragma("unroll")                                                            \
  for (int q = 0; q < 8; ++q) {                                                \
    __builtin_amdgcn_global_load_lds(                                          \
        (__attribute__((address_space(1))) void*)bsrc[q],                      \
        (__attribute__((address_space(3))) void*)(                             \
            &Bs[BUFI][(q * 256 + pwbase) * 8]),                                \
        16, 0, 0);                                                             \
    bsrc[q] += BK;                                                             \
  }                                                                            \
  asm volatile("" ::: "memory");

#define TRANSFORM4(BUFI, S)                                                    \
  {                                                                            \
    f32x4 sa0 = *(const f32x4*)&SF[ktb];                                       \
    f32x4 sa1 = *(const f32x4*)&SF[ktb + 4];                                   \
    f32x4 sc0 = *(const f32x4*)&SH[ktb];                                       \
    f32x4 sc1 = *(const f32x4*)&SH[ktb + 4];                                   \
    ktb += BK;                                                                 \
    _Pragma("unroll")                                                          \
    for (int k = 0; k < 4; ++k) {                                              \
      u16x8 pk;                                                                \
      _Pragma("unroll")                                                        \
      for (int e = 0; e < 4; ++e) {                                            \
        pk[e]     = f2bf(fmaxf(S[2 * k][e]     * sa0[e] + sc0[e], 0.f));       \
        pk[e + 4] = f2bf(fmaxf(S[2 * k + 1][e] * sa1[e] + sc1[e], 0.f));       \
      }                                                                        \
      *(u16x8*)&As[BUFI][awo + k * 2048] = pk;                                 \
    }                                                                          \
  }

#define PRODUCE(BUFI)                                                          \
  do {                                                                         \
    f32x4 S[8];                                                                \
    ISSUE_A8(S);                                                               \
    ISSUE_B8(BUFI);                                                            \
    asm volatile("s_waitcnt vmcnt(8)" ::: "memory");                           \
    __builtin_amdgcn_sched_barrier(0);                                         \
    TRANSFORM4(BUFI, S);                                                       \
    asm volatile("s_waitcnt vmcnt(0) lgkmcnt(0)" ::: "memory");                \
    __builtin_amdgcn_sched_barrier(0);                                         \
  } while (0)

#define MFMA_PHASE(BUFI)                                                       \
  _Pragma("unroll")                                                            \
  for (int kk = 0; kk < 2; ++kk) {                                             \
    const int kx = kk << 5;                                                    \
    bf16x8 af[4], bfr[4];                                                      \
    _Pragma("unroll")                                                          \
    for (int i = 0; i < 4; ++i)                                                \
      af[i] = __builtin_bit_cast(bf16x8,                                       \
                                 *(const u16x8*)&As[BUFI][offA[i] ^ kx]);      \
    _Pragma("unroll")                                                          \
    for (int j = 0; j < 4; ++j)                                                \
      bfr[j] = __builtin_bit_cast(bf16x8,                                      \
                                  *(const u16x8*)&Bs[BUFI][offB[j] ^ kx]);     \
    _Pragma("unroll")                                                          \
    for (int i = 0; i < 4; ++i)                                                \
      _Pragma("unroll")                                                        \
      for (int j = 0; j < 4; ++j)                                              \
        acc[i][j] = __builtin_amdgcn_mfma_f32_16x16x32_bf16(                   \
            af[i], bfr[j], acc[i][j], 0, 0, 0);                                \
  }

  // ---- prologue: producers stage tile 0 into buffers [0] ----
  if (!consumer) PRODUCE(0);
  __builtin_amdgcn_s_barrier();

  // ---- main loop: step t consumes buf t&1; producers stage t+1 -> buf^1 ----
  for (int kt = 0; kt < NKT - 2; kt += 2) {
    if (consumer) { MFMA_PHASE(0); } else { PRODUCE(1); }
    __builtin_amdgcn_s_barrier();
    if (consumer) { MFMA_PHASE(1); } else { PRODUCE(0); }
    __builtin_amdgcn_s_barrier();
  }
  // step 62: stage tile 63 -> buf 1
  if (consumer) { MFMA_PHASE(0); } else { PRODUCE(1); }
  __builtin_amdgcn_s_barrier();
  // step 63: no prefetch
  if (consumer) { MFMA_PHASE(1); }

#undef MFMA_PHASE
#undef PRODUCE
#undef TRANSFORM4
#undef ISSUE_B8
#undef ISSUE_A8

  // epilogue (consumers only): C/D layout col=l&15, row=(l>>4)*4+rr
  if (consumer) {
    const int cl = l & 15;
    const int rg = l >> 4;
#pragma unroll
    for (int j = 0; j < 4; ++j) {
      const int oc = wc * 64 + j * 16 + cl;
      const float bv = bias[oc];
#pragma unroll
      for (int i = 0; i < 4; ++i) {
        const size_t rbase = bm0 + wr * 64 + i * 16 + rg * 4;
#pragma unroll
        for (int rr = 0; rr < 4; ++rr) {
          out[(rbase + rr) * ODIM + oc] = acc[i][j][rr] + bv;
        }
      }
    }
  }
}

extern "C" void kernel_launch(void* const* d_in, const int* in_sizes, int n_in,
                              void* d_out, int out_size, void* d_ws, size_t ws_size,
                              hipStream_t stream) {
  const float* x     = (const float*)d_in[0];
  const float* gamma = (const float*)d_in[1];
  const float* beta  = (const float*)d_in[2];
  const float* W     = (const float*)d_in[3];
  const float* b     = (const float*)d_in[4];
  float* out = (float*)d_out;

  float* psum  = (float*)d_ws;
  float* psq   = psum + (size_t)CHUNKS * DDIM;
  float* scale = psum + 2 * (size_t)CHUNKS * DDIM;
  float* shift = scale + DDIM;
  unsigned short* Wb = (unsigned short*)(shift + DDIM);

  k1_stats<<<dim3(4, CHUNKS), 256, 0, stream>>>(x, psum, psq);
  k2_stats_finalize<<<DDIM / 64, 256, 0, stream>>>(psum, psq, gamma, beta, scale, shift);
  k2_wconv<<<(ODIM * DDIM) / 1024, 256, 0, stream>>>(W, Wb);
  k3_bn_gemm<<<NROWS / BM, 768, 0, stream>>>(x, Wb, scale, shift, b, out);
}